// Round 3
// baseline (181.922 us; speedup 1.0000x reference)
//
#include <hip/hip_runtime.h>

// Problem: B=64, K=17, H=128, W=128, RATIO=0.25, SIGMA=2.0
constexpr int HW     = 16384;            // 128*128
constexpr int NT     = 512;              // threads per block
constexpr int NW     = NT / 64;          // 8 waves per block
constexpr int V4PT   = HW / (NT * 4);    // 8 float4 per thread
constexpr int KTH    = HW - HW / 4;      // 12288 = 1-indexed kth smallest (kthvalue)
constexpr int GTMAX  = HW - KTH;         // 4096 = #(v > thresh)
constexpr int NSLICE = 64 * 17;          // 1088 (b,k) slices
constexpr int NCANDM = 256;              // candidate buffer
constexpr int CAP    = 192;              // stop search when window <= CAP
constexpr int SLOTS  = 8;                // per-thread stash capacity
constexpr int SSTR   = 9;                // stash stride in words (pad: 8 -> 16-way bank conflict)
constexpr float LO0  = 0.735f;           // static bracket around the 0.75-quantile
constexpr float HI0  = 0.770f;           // (validated at runtime; fallback if wrong)

__global__ __launch_bounds__(NT, 4) void wreg_slice(
    const float* __restrict__ pred,
    const float* __restrict__ tgt,
    float* __restrict__ partial)
{
    __shared__ float redf[NW];
    __shared__ int   redi[NW];
    __shared__ int   wcnt[NW];
    __shared__ int   wwin[NW];
    __shared__ int   wovf[NW];
    __shared__ float stash[NT * SSTR];   // 18 KB
    __shared__ float cands[NCANDM];
    __shared__ int   s_ncand;
    __shared__ float s_thresh;

    const int t    = threadIdx.x;
    const int lane = t & 63;
    const int wid  = t >> 6;
    const int bid  = blockIdx.x;
    const float4* t4 = reinterpret_cast<const float4*>(tgt)  + (size_t)bid * (HW / 4);
    const float4* p4 = reinterpret_cast<const float4*>(pred) + (size_t)bid * (HW / 4);
    const int sbase = t * SSTR;

    if (t == 0) s_ncand = 0;

    // ---- Pass 1 (fused): load slice -> vreg, argmax, bracket counts, stash window values ----
    float4 vreg[V4PT];
    float bmax = -1.0f;
    int   bmi  = 0;
    int   cnt_hi = 0;   // #(x > HI0)
    int   nwin   = 0;   // #(LO0 < x <= HI0), true count
    int   ovf    = 0;
    #pragma unroll
    for (int j = 0; j < V4PT; ++j) {
        const int vi = j * NT + t;
        float4 v = t4[vi];
        vreg[j] = v;
        const int base = vi * 4;
        float a[4] = {v.x, v.y, v.z, v.w};
        #pragma unroll
        for (int c = 0; c < 4; ++c) {
            float x = a[c];
            if (x > bmax) { bmax = x; bmi = base + c; }   // per-thread idx increasing -> first
            cnt_hi += (x > HI0) ? 1 : 0;
            if (x > LO0 && x <= HI0) {
                if (nwin < SLOTS) stash[sbase + nwin] = x; else ovf = 1;
                ++nwin;
            }
        }
    }

    // ---- One block-reduction round: argmax + bracket counts + overflow ----
    #pragma unroll
    for (int off = 32; off > 0; off >>= 1) {
        float ov = __shfl_down(bmax, off);
        int   oi = __shfl_down(bmi, off);
        if (ov > bmax || (ov == bmax && oi < bmi)) { bmax = ov; bmi = oi; }
        cnt_hi += __shfl_down(cnt_hi, off);
        nwin   += __shfl_down(nwin, off);
        ovf    |= __shfl_down(ovf, off);
    }
    // NOTE: nwin/cnt_hi/ovf in lanes !=0 are now partial, but only lane 0 publishes.
    if (lane == 0) { redf[wid] = bmax; redi[wid] = bmi; wcnt[wid] = cnt_hi; wwin[wid] = nwin; wovf[wid] = ovf; }
    __syncthreads();
    float mv = redf[0]; int mi = redi[0];
    int g_hi0 = 0, win = 0, anyovf = 0;
    #pragma unroll
    for (int w = 0; w < NW; ++w) {
        if (redf[w] > mv || (redf[w] == mv && redi[w] < mi)) { mv = redf[w]; mi = redi[w]; }
        g_hi0 += wcnt[w]; win += wwin[w]; anyovf |= wovf[w];
    }
    const float cy = (float)(mi >> 7);
    const float cx = (float)(mi & 127);

    // reload this thread's true window count (it was clobbered by the reduce)
    int myn = 0;
    // recompute cheaply from stash? we know it only if <= SLOTS; recount from vreg:
    // (cheap: 32 predicated adds, once)
    #pragma unroll
    for (int j = 0; j < V4PT; ++j) {
        float4 v = vreg[j];
        myn += (v.x > LO0 && v.x <= HI0) ? 1 : 0;
        myn += (v.y > LO0 && v.y <= HI0) ? 1 : 0;
        myn += (v.z > LO0 && v.z <= HI0) ? 1 : 0;
        myn += (v.w > LO0 && v.w <= HI0) ? 1 : 0;
    }

    const bool valid = (!anyovf) && (g_hi0 <= GTMAX) && (g_hi0 + win >= GTMAX + 1);

    float th;
    if (valid) {
        // ---- Fast path: search only the stashed window values ----
        float s[SLOTS];
        #pragma unroll
        for (int i = 0; i < SLOTS; ++i) s[i] = stash[sbase + i];  // garbage beyond myn, guarded below

        float lo = LO0, hi = HI0;
        int g_lo = g_hi0 + win, g_hi = g_hi0;
        bool degen = false;
        while (g_lo - g_hi > CAP) {
            float mid = 0.5f * (lo + hi);
            if (!(mid > lo && mid < hi)) { degen = true; break; }
            int cnt = 0;
            #pragma unroll
            for (int i = 0; i < SLOTS; ++i) cnt += (i < myn && s[i] > mid) ? 1 : 0;
            #pragma unroll
            for (int off = 32; off > 0; off >>= 1) cnt += __shfl_down(cnt, off);
            if (lane == 0) wcnt[wid] = cnt;
            __syncthreads();
            int g = g_hi0;
            #pragma unroll
            for (int w = 0; w < NW; ++w) g += wcnt[w];
            __syncthreads();
            if (g >= GTMAX + 1) { lo = mid; g_lo = g; }
            else                { hi = mid; g_hi = g; }
        }
        if (degen) {
            th = hi;
        } else {
            #pragma unroll
            for (int i = 0; i < SLOTS; ++i) {
                if (i < myn) {
                    float x = s[i];
                    if (x > lo && x <= hi) { int pos = atomicAdd(&s_ncand, 1); cands[pos] = x; }
                }
            }
            __syncthreads();
            const int m = s_ncand;
            const int r = GTMAX;
            for (int i = t; i < m; i += NT) {
                float ci = cands[i];
                int gt = 0, eq = 0;
                for (int j2 = 0; j2 < m; ++j2) {
                    float cj = cands[j2];
                    gt += (cj > ci) ? 1 : 0;
                    eq += (cj == ci) ? 1 : 0;
                }
                int gi = g_hi + gt;
                if (gi <= r && gi + eq >= r + 1) s_thresh = ci;
            }
            __syncthreads();
            th = s_thresh;
        }
    } else {
        // ---- Fallback: full binary search over vreg (any input, bit-exact) ----
        float lo = -1.0f, hi = 1.0e30f;
        int g_lo = HW, g_hi = 0;
        bool degen = false;
        while (g_lo - g_hi > CAP) {
            float mid = 0.5f * (lo + hi);
            if (!(mid > lo && mid < hi)) { degen = true; break; }
            int cnt = 0;
            #pragma unroll
            for (int j = 0; j < V4PT; ++j) {
                float4 v = vreg[j];
                cnt += (v.x > mid) + (v.y > mid) + (v.z > mid) + (v.w > mid);
            }
            #pragma unroll
            for (int off = 32; off > 0; off >>= 1) cnt += __shfl_down(cnt, off);
            if (lane == 0) wcnt[wid] = cnt;
            __syncthreads();
            int g = 0;
            #pragma unroll
            for (int w = 0; w < NW; ++w) g += wcnt[w];
            __syncthreads();
            if (g >= GTMAX + 1) { lo = mid; g_lo = g; }
            else                { hi = mid; g_hi = g; }
        }
        if (degen) {
            th = hi;
        } else {
            #pragma unroll
            for (int j = 0; j < V4PT; ++j) {
                float4 v = vreg[j];
                float a[4] = {v.x, v.y, v.z, v.w};
                #pragma unroll
                for (int c = 0; c < 4; ++c) {
                    float x = a[c];
                    if (x > lo && x <= hi) { int pos = atomicAdd(&s_ncand, 1); cands[pos] = x; }
                }
            }
            __syncthreads();
            const int m = s_ncand;
            const int r = GTMAX;
            for (int i = t; i < m; i += NT) {
                float ci = cands[i];
                int gt = 0, eq = 0;
                for (int j2 = 0; j2 < m; ++j2) {
                    float cj = cands[j2];
                    gt += (cj > ci) ? 1 : 0;
                    eq += (cj == ci) ? 1 : 0;
                }
                int gi = g_hi + gt;
                if (gi <= r && gi + eq >= r + 1) s_thresh = ci;
            }
            __syncthreads();
            th = s_thresh;
        }
    }

    // ---- Final pass: masked MSE vs re-rendered Gaussian ----
    float sum = 0.0f;
    #pragma unroll
    for (int j = 0; j < V4PT; ++j) {
        const int vi = j * NT + t;
        float4 p = p4[vi];
        float4 v = vreg[j];
        const int base = vi * 4;
        float av[4] = {v.x, v.y, v.z, v.w};
        float ap[4] = {p.x, p.y, p.z, p.w};
        #pragma unroll
        for (int c = 0; c < 4; ++c) {
            float x = av[c];
            if (x > th) {
                const int idx = base + c;
                float dy = (float)(idx >> 7) - cy;
                float dx = (float)(idx & 127) - cx;
                float g  = __expf(-(dy * dy + dx * dx) * 0.125f);  // 1/(2*sigma^2) = 1/8
                float d  = ap[c] - g;
                sum += d * d;
            }
        }
    }
    #pragma unroll
    for (int off = 32; off > 0; off >>= 1) sum += __shfl_down(sum, off);
    if (lane == 0) redf[wid] = sum;   // all redf reads completed before earlier barriers
    __syncthreads();
    if (t == 0) {
        float s = 0.0f;
        #pragma unroll
        for (int w = 0; w < NW; ++w) s += redf[w];
        partial[bid] = s;
    }
}

__global__ __launch_bounds__(256) void wreg_final(
    const float* __restrict__ partial, float* __restrict__ out)
{
    __shared__ float red[4];
    const int t = threadIdx.x;
    float s = 0.0f;
    for (int i = t; i < NSLICE; i += 256) s += partial[i];
    for (int off = 32; off > 0; off >>= 1) s += __shfl_down(s, off);
    if ((t & 63) == 0) red[t >> 6] = s;
    __syncthreads();
    if (t == 0)
        out[0] = ((red[0] + red[1]) + (red[2] + red[3]))
                 * (1.0f / ((float)(HW / 4) * (float)NSLICE));  // / pxl_num / (B*K)
}

extern "C" void kernel_launch(void* const* d_in, const int* in_sizes, int n_in,
                              void* d_out, int out_size, void* d_ws, size_t ws_size,
                              hipStream_t stream)
{
    const float* pred = (const float*)d_in[0];   // "output" in reference
    const float* tgt  = (const float*)d_in[1];   // "target"
    float* partial = (float*)d_ws;               // 1088 floats of scratch
    float* out     = (float*)d_out;

    wreg_slice<<<NSLICE, NT, 0, stream>>>(pred, tgt, partial);
    wreg_final<<<1, 256, 0, stream>>>(partial, out);
}